// Round 1
// 88.379 us; speedup vs baseline: 1.0715x; 1.0715x over previous
//
#include <hip/hip_runtime.h>

// Problem: B=4, L=2048, H=8, D=64.
// Reference math collapses to: out[m,q,h,d] = sum_e values[m,e,h,d]
// (softmax row-sum over w is exactly 1; the einsum sums w and e independently).
//
// Single fused kernel, ONE dispatch, zero workspace traffic:
//   grid = 4 m x 16 col-slices x 4 q-chunks = 256 blocks (1 per CU).
//   Each block reduces all 2048 e-rows over its 8-float4 (128 B) column slice,
//   then broadcasts the slice sum to its 512 q rows.
// Read redundancy is 4x (one full column reduction per q-chunk), but the four
// blocks sharing an (m, slice) are 64 apart in blockIdx -> same XCD under the
// %8 round-robin, so repeats are L2 hits. Minimal HBM: 16.8 MB in, 16.8 MB out.

#define Bm     4
#define Lseq   2048
#define C4     128                  // float4 columns per row (H*D/4)
#define SW     8                    // float4 per slice (128 B)
#define SLICES (C4 / SW)            // 16 slices per m
#define QCH    4                    // q chunks
#define QROWS  (Lseq / QCH)         // 512 q rows per block

__global__ __launch_bounds__(256)
void fused_sum_bcast(const float4* __restrict__ v4, float4* __restrict__ out4) {
    const int b  = blockIdx.x;
    const int j  = b >> 6;          // q-chunk 0..3
    const int r  = b & 63;
    const int m  = r >> 4;          // batch 0..3
    const int s0 = (r & (SLICES - 1)) * SW;

    const int t  = threadIdx.x;     // 256 threads
    const int ct = t & (SW - 1);    // 0..7  : float4 col within slice
    const int rt = t >> 3;          // 0..31 : row group

    // ---- reduce all 2048 e-rows of this (m, slice) ----
    // Wave access: 8 rows x 128 B contiguous segments -> full-line coalescing.
    const float4* vp = v4 + ((size_t)m * Lseq + rt) * C4 + s0 + ct;

    float4 acc = make_float4(0.f, 0.f, 0.f, 0.f);
#pragma unroll 8
    for (int i = 0; i < Lseq / 32; ++i) {          // rows rt + 32*i
        float4 x = vp[(size_t)i * 32 * C4];
        acc.x += x.x; acc.y += x.y; acc.z += x.z; acc.w += x.w;
    }

    // ---- fold 32 row-groups per column via LDS tree ----
    __shared__ float4 red[32][SW];
    red[rt][ct] = acc;
    __syncthreads();
#pragma unroll
    for (int s = 16; s >= 1; s >>= 1) {
        if (rt < s) {
            float4 a = red[rt][ct], o = red[rt + s][ct];
            a.x += o.x; a.y += o.y; a.z += o.z; a.w += o.w;
            red[rt][ct] = a;
        }
        __syncthreads();
    }
    const float4 vs = red[0][ct];

    // ---- broadcast to this block's 512 q rows ----
    float4* op = out4 + ((size_t)m * Lseq + j * QROWS + rt) * C4 + s0 + ct;
#pragma unroll
    for (int i = 0; i < QROWS / 32; ++i) {         // 16 float4 stores per thread
        op[(size_t)i * 32 * C4] = vs;
    }
}

extern "C" void kernel_launch(void* const* d_in, const int* in_sizes, int n_in,
                              void* d_out, int out_size, void* d_ws, size_t ws_size,
                              hipStream_t stream) {
    (void)in_sizes; (void)n_in; (void)d_ws; (void)ws_size; (void)out_size;
    // inputs: d_in[0]=queries (unused), d_in[1]=keys (unused), d_in[2]=values
    const float4* values = (const float4*)d_in[2];
    fused_sum_bcast<<<Bm * SLICES * QCH, 256, 0, stream>>>(values, (float4*)d_out);
}